// Round 1
// baseline (323.420 us; speedup 1.0000x reference)
//
#include <hip/hip_runtime.h>

// DeepPoly ReLU relaxation — purely elementwise, memory-bound.
// Traffic: 6 fp32 streams x 16M elems = 402.7 MB -> ~64 us floor at 6.3 TB/s.
// R1: top-5 rocprof dispatches are all ~121us harness poison-fills; our kernel
//     is below them. Timed region ~= 2 fills (240us fixed) + kernel (~82us).
// R4 theory: kernel at ~4.9 TB/s effective. 8192 short-lived blocks each do
//     load -> waitcnt -> compute -> store -> retire: the read and write streams
//     drain at every block boundary instead of staying concurrently in flight.
// R4 change: 2048 persistent blocks (8/CU, 32 waves/CU at <=64 VGPR),
//     grid-stride over 8 tiles/thread with next-tile prefetch: loads for tile
//     k+1 issue before stores of tile k, keeping both directions of HBM
//     traffic continuously occupied.
// Predicted: kernel ~82 -> ~66-70us; bench dur_us 322 -> ~300-308.

typedef float f32x4 __attribute__((ext_vector_type(4)));

__device__ __forceinline__ void relax4(f32x4 xv, f32x4 lv, f32x4 hv,
                                       f32x4& xr, f32x4& lr, f32x4& hr) {
#pragma unroll
    for (int j = 0; j < 4; ++j) {
        float xx = xv[j], l = lv[j], h = hv[j];
        bool crossing = (l < 0.0f) && (h > 0.0f);
        bool inactive = (h <= 0.0f);
        // crossing => h>0, l<0 => h-l > 0. Speculative rcp; selected away otherwise.
        float inv = __builtin_amdgcn_rcpf(h - l);
        float ub_slope = crossing ? (h * inv) : (inactive ? 0.0f : 1.0f);
        float ub_int   = crossing ? (-(l * h) * inv) : 0.0f;
        float lamda    = (l * l > h * h) ? 0.0f : 1.0f;
        float lb_slope = crossing ? lamda : (inactive ? 0.0f : 1.0f);
        float xo = fmaxf(xx, 0.0f);
        float ho = ub_slope * h + ub_int;
        float lo = lb_slope * l;
        xr[j] = xo;
        lr[j] = lo;
        hr[j] = ho;
    }
}

__global__ __launch_bounds__(256) void abstract_relu_kernel(
        const f32x4* __restrict__ x,
        const f32x4* __restrict__ low,
        const f32x4* __restrict__ high,
        f32x4* __restrict__ x_out,
        f32x4* __restrict__ low_out,
        f32x4* __restrict__ high_out,
        int stride,     // gridDim.x * blockDim.x, in f32x4 units
        int iters) {    // n4 / stride (exact; n = 2^24)
    int i = blockIdx.x * blockDim.x + threadIdx.x;

    // Preload tile 0.
    f32x4 cx = __builtin_nontemporal_load(&x[i]);
    f32x4 cl = __builtin_nontemporal_load(&low[i]);
    f32x4 ch = __builtin_nontemporal_load(&high[i]);

    for (int it = 1; it < iters; ++it) {
        int ni = i + stride;
        // Issue next tile's loads BEFORE computing/storing the current tile:
        // these stay in flight under the 3 nontemporal stores below.
        f32x4 nx = __builtin_nontemporal_load(&x[ni]);
        f32x4 nl = __builtin_nontemporal_load(&low[ni]);
        f32x4 nh = __builtin_nontemporal_load(&high[ni]);

        f32x4 xr, lr, hr;
        relax4(cx, cl, ch, xr, lr, hr);
        __builtin_nontemporal_store(xr, &x_out[i]);
        __builtin_nontemporal_store(lr, &low_out[i]);
        __builtin_nontemporal_store(hr, &high_out[i]);

        cx = nx; cl = nl; ch = nh; i = ni;
    }

    // Drain last tile.
    f32x4 xr, lr, hr;
    relax4(cx, cl, ch, xr, lr, hr);
    __builtin_nontemporal_store(xr, &x_out[i]);
    __builtin_nontemporal_store(lr, &low_out[i]);
    __builtin_nontemporal_store(hr, &high_out[i]);
}

extern "C" void kernel_launch(void* const* d_in, const int* in_sizes, int n_in,
                              void* d_out, int out_size, void* d_ws, size_t ws_size,
                              hipStream_t stream) {
    const int n = in_sizes[0];          // 16777216 = 2^24
    const int n4 = n / 4;               // 4,194,304 float4s

    const f32x4* x    = (const f32x4*)d_in[0];
    const f32x4* low  = (const f32x4*)d_in[1];
    const f32x4* high = (const f32x4*)d_in[2];

    float* out = (float*)d_out;         // [relu(x) | low_out | high_out]
    f32x4* x_out    = (f32x4*)(out);
    f32x4* low_out  = (f32x4*)(out + (size_t)n);
    f32x4* high_out = (f32x4*)(out + (size_t)2 * n);

    const int block  = 256;
    const int grid   = 2048;            // 8 blocks/CU -> 32 waves/CU at <=64 VGPR
    const int stride = grid * block;    // 524288 f32x4 per sweep
    const int iters  = n4 / stride;     // 8 (exact for n = 2^24)

    abstract_relu_kernel<<<grid, block, 0, stream>>>(
        x, low, high, x_out, low_out, high_out, stride, iters);
}